// Round 6
// baseline (123.181 us; speedup 1.0000x reference)
//
#include <hip/hip_runtime.h>
#include <math.h>

#define T 1024
#define NB 64

__device__ __forceinline__ float clip01(float v) {
    return fminf(fmaxf(v, 0.0f), 1.0f);
}

__device__ __forceinline__ float wave_reduce_sum(float v) {
    #pragma unroll
    for (int off = 32; off > 0; off >>= 1) v += __shfl_xor(v, off, 64);
    return v;
}

__device__ __forceinline__ float2 wave_reduce_max2(float2 v) {
    #pragma unroll
    for (int off = 32; off > 0; off >>= 1) {
        v.x = fmaxf(v.x, __shfl_xor(v.x, off, 64));
        v.y = fmaxf(v.y, __shfl_xor(v.y, off, 64));
    }
    return v;
}

__device__ __forceinline__ float2 wave_reduce_sum2(float2 v) {
    #pragma unroll
    for (int off = 32; off > 0; off >>= 1) {
        v.x += __shfl_xor(v.x, off, 64);
        v.y += __shfl_xor(v.y, off, 64);
    }
    return v;
}

// ---------------------------------------------------------------------------
// Single kernel, 192 blocks x 256 threads, one block per (branch, batch).
// Handoff: every block seq_cst-stores its encoded r = -(r+1) in [-2,-1] to
// rws[br*64+batch], then seq_cst-loads its batch's other two slots. If both
// are < -0.5 (i.e. written), this block combines and writes out[batch].
// By seq_cst total order, the batch's LAST storer must see the other two =>
// at least one combiner per batch; extra combiners write identical bits
// (all decode the same slot values). No spinning, no grid sync, no 2nd node.
// Unwritten states (0x0 / 0xAA poison = -3e-13) are > -0.5 => no false hits.
// ---------------------------------------------------------------------------
__global__ __launch_bounds__(256, 1) void k_all(
    const float* __restrict__ x1, const float* __restrict__ x2,
    const float* __restrict__ x3,
    const float* __restrict__ t1p, const float* __restrict__ b1p,
    const float* __restrict__ A1_1, const float* __restrict__ A2_1,
    const float* __restrict__ ba1, const float* __restrict__ bb1,
    const float* __restrict__ t2p, const float* __restrict__ b2p,
    const float* __restrict__ A1_2, const float* __restrict__ A2_2,
    const float* __restrict__ ba2, const float* __restrict__ bb2,
    const float* __restrict__ t3p, const float* __restrict__ b3p,
    const float* __restrict__ A1_3, const float* __restrict__ A2_3,
    const float* __restrict__ ba3, const float* __restrict__ bb3,
    const float* __restrict__ A4, const float* __restrict__ beta4p,
    float* __restrict__ rws, float* __restrict__ out)
{
    __shared__ float sS[2 * T];    // 8 KB
    __shared__ float sA1[T];       // 4 KB
    __shared__ float pr0[4], pr1[4];

    const int br    = blockIdx.x >> 6;   // 0..2
    const int batch = blockIdx.x & 63;   // 0..63
    const int tid   = threadIdx.x;
    const int wave  = tid >> 6;
    const int lane  = tid & 63;

    const float *x, *tp, *bp, *a1p, *a2p, *bap, *bbp;
    if (br == 0)      { x = x1; tp = t1p; bp = b1p; a1p = A1_1; a2p = A2_1; bap = ba1; bbp = bb1; }
    else if (br == 1) { x = x2; tp = t2p; bp = b2p; a1p = A1_2; a2p = A2_2; bap = ba2; bbp = bb2; }
    else              { x = x3; tp = t3p; bp = b3p; a1p = A1_3; a2p = A2_3; bap = ba3; bbp = bb3; }

    // Issue all global loads up front.
    const float4 xv  = ((const float4*)(x + (size_t)batch * T))[tid];
    const float4 a1r = ((const float4*)a1p)[tid];
    const float4 a2r = ((const float4*)a2p)[tid];
    const float tt = *tp;
    const float bb = *bp;
    const float beta_a = *bap;
    const float beta_b = *bbp;
    const float sig10 = 1.0f / (1.0f + expf(10.0f));   // sigmoid(-10)

    // --- dual softmax (A1 and A2 together) ---
    float2 mx = make_float2(fmaxf(fmaxf(a1r.x, a1r.y), fmaxf(a1r.z, a1r.w)),
                            fmaxf(fmaxf(a2r.x, a2r.y), fmaxf(a2r.z, a2r.w)));
    mx = wave_reduce_max2(mx);
    if (lane == 0) { pr0[wave] = mx.x; pr1[wave] = mx.y; }
    __syncthreads();
    const float m1 = fmaxf(fmaxf(pr0[0], pr0[1]), fmaxf(pr0[2], pr0[3]));
    const float m2 = fmaxf(fmaxf(pr1[0], pr1[1]), fmaxf(pr1[2], pr1[3]));

    float e10 = expf(a1r.x - m1), e11 = expf(a1r.y - m1);
    float e12 = expf(a1r.z - m1), e13 = expf(a1r.w - m1);
    float e20 = expf(a2r.x - m2), e21 = expf(a2r.y - m2);
    float e22 = expf(a2r.z - m2), e23 = expf(a2r.w - m2);
    float2 sm = make_float2((e10 + e11) + (e12 + e13),
                            (e20 + e21) + (e22 + e23));
    sm = wave_reduce_sum2(sm);
    __syncthreads();                 // pr reuse
    if (lane == 0) { pr0[wave] = sm.x; pr1[wave] = sm.y; }

    // --- sigmoid row (exact mul/sub semantics for the r==b test) ---
    float4 sv;
    {
        float p, r;
        p = __fmul_rn(xv.x, tt); r = __fsub_rn(bb, p); if (r == bb) r = -10.0f;
        sv.x = 1.0f / (1.0f + expf(-r));
        p = __fmul_rn(xv.y, tt); r = __fsub_rn(bb, p); if (r == bb) r = -10.0f;
        sv.y = 1.0f / (1.0f + expf(-r));
        p = __fmul_rn(xv.z, tt); r = __fsub_rn(bb, p); if (r == bb) r = -10.0f;
        sv.z = 1.0f / (1.0f + expf(-r));
        p = __fmul_rn(xv.w, tt); r = __fsub_rn(bb, p); if (r == bb) r = -10.0f;
        sv.w = 1.0f / (1.0f + expf(-r));
    }
    ((float4*)sS)[tid] = sv;
    ((float4*)(sS + T))[tid] = make_float4(sig10, sig10, sig10, sig10);
    __syncthreads();
    const float inv1 = 1.0f / ((pr0[0] + pr0[1]) + (pr0[2] + pr0[3]));
    const float inv2 = 1.0f / ((pr1[0] + pr1[1]) + (pr1[2] + pr1[3]));
    ((float4*)sA1)[tid] = make_float4(e10 * inv1, e11 * inv1, e12 * inv1, e13 * inv1);
    const float4 a2 = make_float4(e20 * inv2, e21 * inv2, e22 * inv2, e23 * inv2);
    __syncthreads();

    // --- correlation: rows 4*tid..4*tid+3, sliding register window ---
    float acc0 = 0.0f, acc1 = 0.0f, acc2 = 0.0f, acc3 = 0.0f;
    float4 u = ((const float4*)sS)[tid];
    #pragma unroll 8
    for (int jv = 0; jv < T / 4; ++jv) {
        const float4 a = ((const float4*)sA1)[jv];        // uniform -> broadcast
        const float4 v = ((const float4*)sS)[tid + jv + 1];
        acc0 = fmaf(a.x, u.x, acc0); acc0 = fmaf(a.y, u.y, acc0);
        acc0 = fmaf(a.z, u.z, acc0); acc0 = fmaf(a.w, u.w, acc0);
        acc1 = fmaf(a.x, u.y, acc1); acc1 = fmaf(a.y, u.z, acc1);
        acc1 = fmaf(a.z, u.w, acc1); acc1 = fmaf(a.w, v.x, acc1);
        acc2 = fmaf(a.x, u.z, acc2); acc2 = fmaf(a.y, u.w, acc2);
        acc2 = fmaf(a.z, v.x, acc2); acc2 = fmaf(a.w, v.y, acc2);
        acc3 = fmaf(a.x, u.w, acc3); acc3 = fmaf(a.y, v.x, acc3);
        acc3 = fmaf(a.z, v.y, acc3); acc3 = fmaf(a.w, v.z, acc3);
        u = v;
    }

    // --- epilogue: wb2 for this (branch, batch) ---
    float act0 = clip01(1.0f - beta_a + acc0);
    float act1 = clip01(1.0f - beta_a + acc1);
    float act2 = clip01(1.0f - beta_a + acc2);
    float act3 = clip01(1.0f - beta_a + acc3);

    float part = a2.x * (1.0f - act0) + a2.y * (1.0f - act1)
               + a2.z * (1.0f - act2) + a2.w * (1.0f - act3);
    part = wave_reduce_sum(part);
    __syncthreads();                 // pr0 reuse
    if (lane == 0) pr0[wave] = part;
    __syncthreads();

    if (tid == 0) {
        float tot = (pr0[0] + pr0[1]) + (pr0[2] + pr0[3]);
        float r_self = clip01(beta_b - tot);
        float enc_self = -(r_self + 1.0f);            // in [-2,-1]

        // Publish own slot (seq_cst so the last storer must see the others).
        __hip_atomic_store(&rws[br * NB + batch], enc_self,
                           __ATOMIC_SEQ_CST, __HIP_MEMORY_SCOPE_AGENT);

        const int o1 = (br == 0) ? 1 : 0;
        const int o2 = (br == 2) ? 1 : 2;
        float ea = __hip_atomic_load(&rws[o1 * NB + batch],
                                     __ATOMIC_SEQ_CST, __HIP_MEMORY_SCOPE_AGENT);
        float eb = __hip_atomic_load(&rws[o2 * NB + batch],
                                     __ATOMIC_SEQ_CST, __HIP_MEMORY_SCOPE_AGENT);

        if (ea < -0.5f && eb < -0.5f) {
            // All three slots written: this block combines (possibly not
            // alone -- all combiners decode identical slot bits).
            float enc[3];
            enc[br] = enc_self; enc[o1] = ea; enc[o2] = eb;
            float r0 = -enc[0] - 1.0f;
            float r1 = -enc[1] - 1.0f;
            float r2 = -enc[2] - 1.0f;

            float a4_0 = A4[0], a4_1 = A4[1], a4_2 = A4[2];
            float m = fmaxf(a4_0, fmaxf(a4_1, a4_2));
            float f0 = expf(a4_0 - m), f1 = expf(a4_1 - m), f2 = expf(a4_2 - m);
            float inv = 1.0f / ((f0 + f1) + f2);
            float beta4 = *beta4p;
            float wb4 = beta4 - (f0 * inv * (1.0f - r0)
                               + f1 * inv * (1.0f - r1)
                               + f2 * inv * (1.0f - r2));
            out[batch] = clip01(wb4);
        }
    }
}

extern "C" void kernel_launch(void* const* d_in, const int* in_sizes, int n_in,
                              void* d_out, int out_size, void* d_ws, size_t ws_size,
                              hipStream_t stream) {
    const float* x1    = (const float*)d_in[0];
    const float* x2    = (const float*)d_in[1];
    const float* x3    = (const float*)d_in[2];
    const float* t1    = (const float*)d_in[3];
    const float* b1    = (const float*)d_in[4];
    const float* A1_1  = (const float*)d_in[5];
    const float* A2_1  = (const float*)d_in[6];
    const float* be1a  = (const float*)d_in[7];
    const float* be1b  = (const float*)d_in[8];
    const float* t2    = (const float*)d_in[9];
    const float* b2    = (const float*)d_in[10];
    const float* A1_2  = (const float*)d_in[11];
    const float* A2_2  = (const float*)d_in[12];
    const float* be2a  = (const float*)d_in[13];
    const float* be2b  = (const float*)d_in[14];
    const float* t3    = (const float*)d_in[15];
    const float* b3    = (const float*)d_in[16];
    const float* A1_3  = (const float*)d_in[17];
    const float* A2_3  = (const float*)d_in[18];
    const float* be3a  = (const float*)d_in[19];
    const float* be3b  = (const float*)d_in[20];
    const float* A4    = (const float*)d_in[21];
    const float* beta4 = (const float*)d_in[22];

    float* rws = (float*)d_ws;          // 3*64 floats: encoded per-branch wb2

    k_all<<<192, 256, 0, stream>>>(
        x1, x2, x3,
        t1, b1, A1_1, A2_1, be1a, be1b,
        t2, b2, A1_2, A2_2, be2a, be2b,
        t3, b3, A1_3, A2_3, be3a, be3b,
        A4, beta4, rws, (float*)d_out);
}

// Round 7
// 114.316 us; speedup vs baseline: 1.0775x; 1.0775x over previous
//
#include <hip/hip_runtime.h>
#include <math.h>

#define T 1024
#define NB 64

__device__ __forceinline__ float clip01(float v) {
    return fminf(fmaxf(v, 0.0f), 1.0f);
}

__device__ __forceinline__ float wave_reduce_sum(float v) {
    #pragma unroll
    for (int off = 32; off > 0; off >>= 1) v += __shfl_xor(v, off, 64);
    return v;
}

__device__ __forceinline__ float2 wave_reduce_max2(float2 v) {
    #pragma unroll
    for (int off = 32; off > 0; off >>= 1) {
        v.x = fmaxf(v.x, __shfl_xor(v.x, off, 64));
        v.y = fmaxf(v.y, __shfl_xor(v.y, off, 64));
    }
    return v;
}

__device__ __forceinline__ float2 wave_reduce_sum2(float2 v) {
    #pragma unroll
    for (int off = 32; off > 0; off >>= 1) {
        v.x += __shfl_xor(v.x, off, 64);
        v.y += __shfl_xor(v.y, off, 64);
    }
    return v;
}

// uniform-lane broadcast of a float held in VGPRs (VALU, no LDS traffic)
__device__ __forceinline__ float bcast_lane(float v, int lane) {
    return __uint_as_float(
        (unsigned)__builtin_amdgcn_readlane((int)__float_as_uint(v), lane));
}

// ---------------------------------------------------------------------------
// Branch kernel (R3 structure): 192 blocks x 256 threads, one block per
// (branch, batch). In-block softmax of A1/A2, S_ext in LDS, then the
// correlation loop. Hot-loop change vs R3: the A-vector is broadcast from
// REGISTERS via v_readlane (uniform lane index) instead of a second
// ds_read_b128 -- halves LDS-pipe traffic in the loop (the measured
// bottleneck: 2048 b128/CU x ~12cyc ~= 10.2us -> ~5.1us).
// Each lane stages A-chunks {l, 64+l, 128+l, 192+l} (identical across the
// 4 waves) with a one-time 4x ds_read_b128.
// ---------------------------------------------------------------------------
__global__ __launch_bounds__(256, 1) void k_branch_fused(
    const float* __restrict__ x1, const float* __restrict__ x2,
    const float* __restrict__ x3,
    const float* __restrict__ t1p, const float* __restrict__ b1p,
    const float* __restrict__ A1_1, const float* __restrict__ A2_1,
    const float* __restrict__ ba1, const float* __restrict__ bb1,
    const float* __restrict__ t2p, const float* __restrict__ b2p,
    const float* __restrict__ A1_2, const float* __restrict__ A2_2,
    const float* __restrict__ ba2, const float* __restrict__ bb2,
    const float* __restrict__ t3p, const float* __restrict__ b3p,
    const float* __restrict__ A1_3, const float* __restrict__ A2_3,
    const float* __restrict__ ba3, const float* __restrict__ bb3,
    float* __restrict__ rws)
{
    __shared__ float sS[2 * T];    // 8 KB
    __shared__ float sA1[T];       // 4 KB
    __shared__ float pr0[4], pr1[4];

    const int br    = blockIdx.x >> 6;   // 0..2
    const int batch = blockIdx.x & 63;   // 0..63
    const int tid   = threadIdx.x;
    const int wave  = tid >> 6;
    const int lane  = tid & 63;

    const float *x, *tp, *bp, *a1p, *a2p, *bap, *bbp;
    if (br == 0)      { x = x1; tp = t1p; bp = b1p; a1p = A1_1; a2p = A2_1; bap = ba1; bbp = bb1; }
    else if (br == 1) { x = x2; tp = t2p; bp = b2p; a1p = A1_2; a2p = A2_2; bap = ba2; bbp = bb2; }
    else              { x = x3; tp = t3p; bp = b3p; a1p = A1_3; a2p = A2_3; bap = ba3; bbp = bb3; }

    // Issue all global loads up front.
    const float4 xv  = ((const float4*)(x + (size_t)batch * T))[tid];
    const float4 a1r = ((const float4*)a1p)[tid];
    const float4 a2r = ((const float4*)a2p)[tid];
    const float tt = *tp;
    const float bb = *bp;
    const float beta_a = *bap;
    const float beta_b = *bbp;
    const float sig10 = 1.0f / (1.0f + expf(10.0f));   // sigmoid(-10)

    // --- dual softmax (A1 and A2 together) ---
    float2 mx = make_float2(fmaxf(fmaxf(a1r.x, a1r.y), fmaxf(a1r.z, a1r.w)),
                            fmaxf(fmaxf(a2r.x, a2r.y), fmaxf(a2r.z, a2r.w)));
    mx = wave_reduce_max2(mx);
    if (lane == 0) { pr0[wave] = mx.x; pr1[wave] = mx.y; }
    __syncthreads();
    const float m1 = fmaxf(fmaxf(pr0[0], pr0[1]), fmaxf(pr0[2], pr0[3]));
    const float m2 = fmaxf(fmaxf(pr1[0], pr1[1]), fmaxf(pr1[2], pr1[3]));

    float e10 = expf(a1r.x - m1), e11 = expf(a1r.y - m1);
    float e12 = expf(a1r.z - m1), e13 = expf(a1r.w - m1);
    float e20 = expf(a2r.x - m2), e21 = expf(a2r.y - m2);
    float e22 = expf(a2r.z - m2), e23 = expf(a2r.w - m2);
    float2 sm = make_float2((e10 + e11) + (e12 + e13),
                            (e20 + e21) + (e22 + e23));
    sm = wave_reduce_sum2(sm);
    __syncthreads();                 // pr reuse
    if (lane == 0) { pr0[wave] = sm.x; pr1[wave] = sm.y; }

    // --- sigmoid row (exact mul/sub semantics for the r==b test) ---
    float4 sv;
    {
        float p, r;
        p = __fmul_rn(xv.x, tt); r = __fsub_rn(bb, p); if (r == bb) r = -10.0f;
        sv.x = 1.0f / (1.0f + expf(-r));
        p = __fmul_rn(xv.y, tt); r = __fsub_rn(bb, p); if (r == bb) r = -10.0f;
        sv.y = 1.0f / (1.0f + expf(-r));
        p = __fmul_rn(xv.z, tt); r = __fsub_rn(bb, p); if (r == bb) r = -10.0f;
        sv.z = 1.0f / (1.0f + expf(-r));
        p = __fmul_rn(xv.w, tt); r = __fsub_rn(bb, p); if (r == bb) r = -10.0f;
        sv.w = 1.0f / (1.0f + expf(-r));
    }
    ((float4*)sS)[tid] = sv;
    ((float4*)(sS + T))[tid] = make_float4(sig10, sig10, sig10, sig10);
    __syncthreads();
    const float inv1 = 1.0f / ((pr0[0] + pr0[1]) + (pr0[2] + pr0[3]));
    const float inv2 = 1.0f / ((pr1[0] + pr1[1]) + (pr1[2] + pr1[3]));
    ((float4*)sA1)[tid] = make_float4(e10 * inv1, e11 * inv1, e12 * inv1, e13 * inv1);
    const float4 a2 = make_float4(e20 * inv2, e21 * inv2, e22 * inv2, e23 * inv2);
    __syncthreads();

    // --- stage A into registers: lane l holds chunks l, 64+l, 128+l, 192+l
    //     (same in every wave, so readlane within any wave sees all of A) ---
    float4 va0 = ((const float4*)sA1)[lane];
    float4 va1 = ((const float4*)sA1)[64 + lane];
    float4 va2 = ((const float4*)sA1)[128 + lane];
    float4 va3 = ((const float4*)sA1)[192 + lane];

    // --- correlation: rows 4*tid..4*tid+3, sliding register window.
    //     A comes from readlane broadcast (VALU); only the window read
    //     touches the LDS pipe. ---
    float acc0 = 0.0f, acc1 = 0.0f, acc2 = 0.0f, acc3 = 0.0f;
    float4 u = ((const float4*)sS)[tid];

    #define CORR_QUARTER(VA, Q)                                              \
        _Pragma("unroll 8")                                                  \
        for (int jg = 0; jg < 64; ++jg) {                                    \
            const int jv = (Q)*64 + jg;                                      \
            float ax = bcast_lane(VA.x, jg);                                 \
            float ay = bcast_lane(VA.y, jg);                                 \
            float az = bcast_lane(VA.z, jg);                                 \
            float aw = bcast_lane(VA.w, jg);                                 \
            const float4 v = ((const float4*)sS)[tid + jv + 1];              \
            acc0 = fmaf(ax, u.x, acc0); acc0 = fmaf(ay, u.y, acc0);          \
            acc0 = fmaf(az, u.z, acc0); acc0 = fmaf(aw, u.w, acc0);          \
            acc1 = fmaf(ax, u.y, acc1); acc1 = fmaf(ay, u.z, acc1);          \
            acc1 = fmaf(az, u.w, acc1); acc1 = fmaf(aw, v.x, acc1);          \
            acc2 = fmaf(ax, u.z, acc2); acc2 = fmaf(ay, u.w, acc2);          \
            acc2 = fmaf(az, v.x, acc2); acc2 = fmaf(aw, v.y, acc2);          \
            acc3 = fmaf(ax, u.w, acc3); acc3 = fmaf(ay, v.x, acc3);          \
            acc3 = fmaf(az, v.y, acc3); acc3 = fmaf(aw, v.z, acc3);          \
            u = v;                                                           \
        }

    CORR_QUARTER(va0, 0)
    CORR_QUARTER(va1, 1)
    CORR_QUARTER(va2, 2)
    CORR_QUARTER(va3, 3)
    #undef CORR_QUARTER

    // --- epilogue: wb2 for this (branch, batch) ---
    float act0 = clip01(1.0f - beta_a + acc0);
    float act1 = clip01(1.0f - beta_a + acc1);
    float act2 = clip01(1.0f - beta_a + acc2);
    float act3 = clip01(1.0f - beta_a + acc3);

    float part = a2.x * (1.0f - act0) + a2.y * (1.0f - act1)
               + a2.z * (1.0f - act2) + a2.w * (1.0f - act3);
    part = wave_reduce_sum(part);
    __syncthreads();                 // pr0 reuse
    if (lane == 0) pr0[wave] = part;
    __syncthreads();
    if (tid == 0) {
        float tot = (pr0[0] + pr0[1]) + (pr0[2] + pr0[3]);
        rws[br * NB + batch] = clip01(beta_b - tot);
    }
}

// ---------------------------------------------------------------------------
// Final 3-way softmax combine. 1 block x 64 threads.
// ---------------------------------------------------------------------------
__global__ __launch_bounds__(64) void k_final(
    const float* __restrict__ A4, const float* __restrict__ beta4p,
    const float* __restrict__ rws, float* __restrict__ out)
{
    int b = threadIdx.x;
    float a0 = A4[0], a1 = A4[1], a2 = A4[2];
    float m = fmaxf(a0, fmaxf(a1, a2));
    float e0 = expf(a0 - m), e1 = expf(a1 - m), e2 = expf(a2 - m);
    float inv = 1.0f / ((e0 + e1) + e2);
    float beta4 = *beta4p;
    float r0 = rws[0 * NB + b];
    float r1 = rws[1 * NB + b];
    float r2 = rws[2 * NB + b];
    float wb4 = beta4 - (e0 * inv * (1.0f - r0)
                       + e1 * inv * (1.0f - r1)
                       + e2 * inv * (1.0f - r2));
    out[b] = clip01(wb4);
}

extern "C" void kernel_launch(void* const* d_in, const int* in_sizes, int n_in,
                              void* d_out, int out_size, void* d_ws, size_t ws_size,
                              hipStream_t stream) {
    const float* x1    = (const float*)d_in[0];
    const float* x2    = (const float*)d_in[1];
    const float* x3    = (const float*)d_in[2];
    const float* t1    = (const float*)d_in[3];
    const float* b1    = (const float*)d_in[4];
    const float* A1_1  = (const float*)d_in[5];
    const float* A2_1  = (const float*)d_in[6];
    const float* be1a  = (const float*)d_in[7];
    const float* be1b  = (const float*)d_in[8];
    const float* t2    = (const float*)d_in[9];
    const float* b2    = (const float*)d_in[10];
    const float* A1_2  = (const float*)d_in[11];
    const float* A2_2  = (const float*)d_in[12];
    const float* be2a  = (const float*)d_in[13];
    const float* be2b  = (const float*)d_in[14];
    const float* t3    = (const float*)d_in[15];
    const float* b3    = (const float*)d_in[16];
    const float* A1_3  = (const float*)d_in[17];
    const float* A2_3  = (const float*)d_in[18];
    const float* be3a  = (const float*)d_in[19];
    const float* be3b  = (const float*)d_in[20];
    const float* A4    = (const float*)d_in[21];
    const float* beta4 = (const float*)d_in[22];

    float* rws = (float*)d_ws;          // 3*64 floats: per-branch wb2

    k_branch_fused<<<192, 256, 0, stream>>>(
        x1, x2, x3,
        t1, b1, A1_1, A2_1, be1a, be1b,
        t2, b2, A1_2, A2_2, be2a, be2b,
        t3, b3, A1_3, A2_3, be3a, be3b,
        rws);

    k_final<<<1, 64, 0, stream>>>(A4, beta4, rws, (float*)d_out);
}

// Round 8
// 112.500 us; speedup vs baseline: 1.0949x; 1.0161x over previous
//
#include <hip/hip_runtime.h>
#include <math.h>

#define T 1024
#define NB 64

__device__ __forceinline__ float clip01(float v) {
    return fminf(fmaxf(v, 0.0f), 1.0f);
}

__device__ __forceinline__ float wave_reduce_sum(float v) {
    #pragma unroll
    for (int off = 32; off > 0; off >>= 1) v += __shfl_xor(v, off, 64);
    return v;
}

__device__ __forceinline__ float2 wave_reduce_max2(float2 v) {
    #pragma unroll
    for (int off = 32; off > 0; off >>= 1) {
        v.x = fmaxf(v.x, __shfl_xor(v.x, off, 64));
        v.y = fmaxf(v.y, __shfl_xor(v.y, off, 64));
    }
    return v;
}

__device__ __forceinline__ float2 wave_reduce_sum2(float2 v) {
    #pragma unroll
    for (int off = 32; off > 0; off >>= 1) {
        v.x += __shfl_xor(v.x, off, 64);
        v.y += __shfl_xor(v.y, off, 64);
    }
    return v;
}

// ---------------------------------------------------------------------------
// Fused branch kernel (measured-best R3 structure): one block per
// (branch, batch) = 192 blocks x 256 thr.
//   1. in-block softmax of A1 (-> LDS) and A2 (-> regs)   [redundant, ~free]
//   2. S_ext[2T] in LDS (sigmoid(b - x*t), exact r==b -> -10 semantics)
//   3. sliding-register-window correlation, 4 rows/thread, 16 FMA/iter
//   4. clip + A2-weighted shuffle reduce -> rws[br*64+batch]
// ---------------------------------------------------------------------------
__global__ __launch_bounds__(256, 1) void k_branch_fused(
    const float* __restrict__ x1, const float* __restrict__ x2,
    const float* __restrict__ x3,
    const float* __restrict__ t1p, const float* __restrict__ b1p,
    const float* __restrict__ A1_1, const float* __restrict__ A2_1,
    const float* __restrict__ ba1, const float* __restrict__ bb1,
    const float* __restrict__ t2p, const float* __restrict__ b2p,
    const float* __restrict__ A1_2, const float* __restrict__ A2_2,
    const float* __restrict__ ba2, const float* __restrict__ bb2,
    const float* __restrict__ t3p, const float* __restrict__ b3p,
    const float* __restrict__ A1_3, const float* __restrict__ A2_3,
    const float* __restrict__ ba3, const float* __restrict__ bb3,
    float* __restrict__ rws)
{
    __shared__ float sS[2 * T];    // 8 KB
    __shared__ float sA1[T];       // 4 KB
    __shared__ float pr0[4], pr1[4];

    const int br    = blockIdx.x >> 6;   // 0..2
    const int batch = blockIdx.x & 63;   // 0..63
    const int tid   = threadIdx.x;
    const int wave  = tid >> 6;
    const int lane  = tid & 63;

    const float *x, *tp, *bp, *a1p, *a2p, *bap, *bbp;
    if (br == 0)      { x = x1; tp = t1p; bp = b1p; a1p = A1_1; a2p = A2_1; bap = ba1; bbp = bb1; }
    else if (br == 1) { x = x2; tp = t2p; bp = b2p; a1p = A1_2; a2p = A2_2; bap = ba2; bbp = bb2; }
    else              { x = x3; tp = t3p; bp = b3p; a1p = A1_3; a2p = A2_3; bap = ba3; bbp = bb3; }

    // Issue all global loads up front.
    const float4 xv  = ((const float4*)(x + (size_t)batch * T))[tid];
    const float4 a1r = ((const float4*)a1p)[tid];
    const float4 a2r = ((const float4*)a2p)[tid];
    const float tt = *tp;
    const float bb = *bp;
    const float beta_a = *bap;
    const float beta_b = *bbp;
    const float sig10 = 1.0f / (1.0f + expf(10.0f));   // sigmoid(-10)

    // --- dual softmax (A1 and A2 together) ---
    float2 mx = make_float2(fmaxf(fmaxf(a1r.x, a1r.y), fmaxf(a1r.z, a1r.w)),
                            fmaxf(fmaxf(a2r.x, a2r.y), fmaxf(a2r.z, a2r.w)));
    mx = wave_reduce_max2(mx);
    if (lane == 0) { pr0[wave] = mx.x; pr1[wave] = mx.y; }
    __syncthreads();
    const float m1 = fmaxf(fmaxf(pr0[0], pr0[1]), fmaxf(pr0[2], pr0[3]));
    const float m2 = fmaxf(fmaxf(pr1[0], pr1[1]), fmaxf(pr1[2], pr1[3]));

    float e10 = expf(a1r.x - m1), e11 = expf(a1r.y - m1);
    float e12 = expf(a1r.z - m1), e13 = expf(a1r.w - m1);
    float e20 = expf(a2r.x - m2), e21 = expf(a2r.y - m2);
    float e22 = expf(a2r.z - m2), e23 = expf(a2r.w - m2);
    float2 sm = make_float2((e10 + e11) + (e12 + e13),
                            (e20 + e21) + (e22 + e23));
    sm = wave_reduce_sum2(sm);
    __syncthreads();                 // pr reuse
    if (lane == 0) { pr0[wave] = sm.x; pr1[wave] = sm.y; }

    // --- sigmoid row (exact mul/sub semantics for the r==b test) ---
    float4 sv;
    {
        float p, r;
        p = __fmul_rn(xv.x, tt); r = __fsub_rn(bb, p); if (r == bb) r = -10.0f;
        sv.x = 1.0f / (1.0f + expf(-r));
        p = __fmul_rn(xv.y, tt); r = __fsub_rn(bb, p); if (r == bb) r = -10.0f;
        sv.y = 1.0f / (1.0f + expf(-r));
        p = __fmul_rn(xv.z, tt); r = __fsub_rn(bb, p); if (r == bb) r = -10.0f;
        sv.z = 1.0f / (1.0f + expf(-r));
        p = __fmul_rn(xv.w, tt); r = __fsub_rn(bb, p); if (r == bb) r = -10.0f;
        sv.w = 1.0f / (1.0f + expf(-r));
    }
    ((float4*)sS)[tid] = sv;
    ((float4*)(sS + T))[tid] = make_float4(sig10, sig10, sig10, sig10);
    __syncthreads();
    const float inv1 = 1.0f / ((pr0[0] + pr0[1]) + (pr0[2] + pr0[3]));
    const float inv2 = 1.0f / ((pr1[0] + pr1[1]) + (pr1[2] + pr1[3]));
    ((float4*)sA1)[tid] = make_float4(e10 * inv1, e11 * inv1, e12 * inv1, e13 * inv1);
    const float4 a2 = make_float4(e20 * inv2, e21 * inv2, e22 * inv2, e23 * inv2);
    __syncthreads();

    // --- correlation: rows 4*tid..4*tid+3, sliding register window ---
    float acc0 = 0.0f, acc1 = 0.0f, acc2 = 0.0f, acc3 = 0.0f;
    float4 u = ((const float4*)sS)[tid];
    #pragma unroll 8
    for (int jv = 0; jv < T / 4; ++jv) {
        const float4 a = ((const float4*)sA1)[jv];        // uniform -> broadcast
        const float4 v = ((const float4*)sS)[tid + jv + 1];
        acc0 = fmaf(a.x, u.x, acc0); acc0 = fmaf(a.y, u.y, acc0);
        acc0 = fmaf(a.z, u.z, acc0); acc0 = fmaf(a.w, u.w, acc0);
        acc1 = fmaf(a.x, u.y, acc1); acc1 = fmaf(a.y, u.z, acc1);
        acc1 = fmaf(a.z, u.w, acc1); acc1 = fmaf(a.w, v.x, acc1);
        acc2 = fmaf(a.x, u.z, acc2); acc2 = fmaf(a.y, u.w, acc2);
        acc2 = fmaf(a.z, v.x, acc2); acc2 = fmaf(a.w, v.y, acc2);
        acc3 = fmaf(a.x, u.w, acc3); acc3 = fmaf(a.y, v.x, acc3);
        acc3 = fmaf(a.z, v.y, acc3); acc3 = fmaf(a.w, v.z, acc3);
        u = v;
    }

    // --- epilogue ---
    float act0 = clip01(1.0f - beta_a + acc0);
    float act1 = clip01(1.0f - beta_a + acc1);
    float act2 = clip01(1.0f - beta_a + acc2);
    float act3 = clip01(1.0f - beta_a + acc3);

    float part = a2.x * (1.0f - act0) + a2.y * (1.0f - act1)
               + a2.z * (1.0f - act2) + a2.w * (1.0f - act3);
    part = wave_reduce_sum(part);
    __syncthreads();                 // pr0 reuse
    if (lane == 0) pr0[wave] = part;
    __syncthreads();
    if (tid == 0) {
        float tot = (pr0[0] + pr0[1]) + (pr0[2] + pr0[3]);
        rws[br * NB + batch] = clip01(beta_b - tot);
    }
}

// ---------------------------------------------------------------------------
// Final 3-way softmax combine. 1 block x 64 threads.
// ---------------------------------------------------------------------------
__global__ __launch_bounds__(64) void k_final(
    const float* __restrict__ A4, const float* __restrict__ beta4p,
    const float* __restrict__ rws, float* __restrict__ out)
{
    int b = threadIdx.x;
    float a0 = A4[0], a1 = A4[1], a2 = A4[2];
    float m = fmaxf(a0, fmaxf(a1, a2));
    float e0 = expf(a0 - m), e1 = expf(a1 - m), e2 = expf(a2 - m);
    float inv = 1.0f / ((e0 + e1) + e2);
    float beta4 = *beta4p;
    float r0 = rws[0 * NB + b];
    float r1 = rws[1 * NB + b];
    float r2 = rws[2 * NB + b];
    float wb4 = beta4 - (e0 * inv * (1.0f - r0)
                       + e1 * inv * (1.0f - r1)
                       + e2 * inv * (1.0f - r2));
    out[b] = clip01(wb4);
}

extern "C" void kernel_launch(void* const* d_in, const int* in_sizes, int n_in,
                              void* d_out, int out_size, void* d_ws, size_t ws_size,
                              hipStream_t stream) {
    const float* x1    = (const float*)d_in[0];
    const float* x2    = (const float*)d_in[1];
    const float* x3    = (const float*)d_in[2];
    const float* t1    = (const float*)d_in[3];
    const float* b1    = (const float*)d_in[4];
    const float* A1_1  = (const float*)d_in[5];
    const float* A2_1  = (const float*)d_in[6];
    const float* be1a  = (const float*)d_in[7];
    const float* be1b  = (const float*)d_in[8];
    const float* t2    = (const float*)d_in[9];
    const float* b2    = (const float*)d_in[10];
    const float* A1_2  = (const float*)d_in[11];
    const float* A2_2  = (const float*)d_in[12];
    const float* be2a  = (const float*)d_in[13];
    const float* be2b  = (const float*)d_in[14];
    const float* t3    = (const float*)d_in[15];
    const float* b3    = (const float*)d_in[16];
    const float* A1_3  = (const float*)d_in[17];
    const float* A2_3  = (const float*)d_in[18];
    const float* be3a  = (const float*)d_in[19];
    const float* be3b  = (const float*)d_in[20];
    const float* A4    = (const float*)d_in[21];
    const float* beta4 = (const float*)d_in[22];

    float* rws = (float*)d_ws;          // 3*64 floats: per-branch wb2

    k_branch_fused<<<192, 256, 0, stream>>>(
        x1, x2, x3,
        t1, b1, A1_1, A2_1, be1a, be1b,
        t2, b2, A1_2, A2_2, be2a, be2b,
        t3, b3, A1_3, A2_3, be3a, be3b,
        rws);

    k_final<<<1, 64, 0, stream>>>(A4, beta4, rws, (float*)d_out);
}